// Round 7
// baseline (126.130 us; speedup 1.0000x reference)
//
#include <hip/hip_runtime.h>
#include <hip/hip_bf16.h>
#include <math.h>

#define NPIX 65536      // 256*256
#define HEPS (6.4f / 255.0f)

typedef __bf16 bf16x8 __attribute__((ext_vector_type(8)));
typedef float  f32x4  __attribute__((ext_vector_type(4)));
typedef float  f32x2  __attribute__((ext_vector_type(2)));

__device__ __forceinline__ float clamp01(float x) { return fminf(fmaxf(x, 0.f), 1.f); }

// grid: 24*SEGB blocks, 256 threads (4 waves). Round-5 structure (measured
// 43.9 us at SEGB=32); SEGB=64 doubles the grid so all 4 block-slots/CU
// (LDS 35.8KB, VGPR~104 -> 4 waves/SIMD) stay filled: 16 waves/CU resident.
// Each wave computes the full 64x64 histogram for its NIT*64 pixels via 4x4
// tiles of mfma_f32_16x16x32_bf16. Epilogue: vectorized slab tree, partial
// stored in FRAGMENT-PERMUTED layout (coalesced b128); loss kernel un-permutes.
// Block 0 zero-inits the 16-float control region (norms/acc/counter).
template <int SEGB>
__global__ __launch_bounds__(256) void hist_mfma(const float* __restrict__ rgbd,
                                                 float* __restrict__ P,
                                                 float* __restrict__ ctrl) {
  constexpr int PPB = NPIX / SEGB;       // pixels per block
  constexpr int NIT = PPB / 4 / 64;      // iters per wave
  const int blk = blockIdx.x;
  const int seg = blk & (SEGB - 1);
  const int bc  = blk / SEGB;     // 0..23
  const int b = bc / 3;
  const int c = bc - 3 * b;
  const int t = threadIdx.x;
  const int l = t & 63;
  const int w = t >> 6;           // wave 0..3

  if (blk == 0 && t < 16) ctrl[t] = 0.f;   // norms[8], acc, counter, pad

  __shared__ float stage[4][3][64];   // per-wave u50/v50/iy staging
  __shared__ f32x4 slab[2][16][64];   // reduction slabs (fragment layout)

  const float* __restrict__ base = rgbd + (size_t)b * (4 * NPIX);

  f32x4 acc[16];
#pragma unroll
  for (int i = 0; i < 16; ++i) acc[i] = (f32x4){0.f, 0.f, 0.f, 0.f};

  const int halfq = l & 15;   // output col within 16-tile
  const int grp   = l >> 4;   // k-group / output row group
  const float d50_0   = (-3.f + (float)halfq * (6.f / 63.f)) * 50.f;  // delta/sigma
  const float dstep50 = (16.f * 6.f / 63.f) * 50.f;
  const f32x2 one2 = {1.f, 1.f};

  const int p0 = seg * PPB + w * (PPB / 4);

  float pr = base[p0 + l];
  float pg = base[NPIX + p0 + l];
  float pb = base[2 * NPIX + p0 + l];

  for (int it = 0; it < NIT; ++it) {
    // ---- per-pixel scalars ----
    float r  = clamp01(fmaf(pr, 0.5f, 0.5f));
    float g  = clamp01(fmaf(pg, 0.5f, 0.5f));
    float bl = clamp01(fmaf(pb, 0.5f, 0.5f));
    float iy = sqrtf(fmaf(r, r, fmaf(g, g, fmaf(bl, bl, HEPS))));
    float lr = __logf(r + HEPS);
    float lg = __logf(g + HEPS);
    float lb = __logf(bl + HEPS);
    float u, v;
    if (c == 0)      { u = lr - lg; v = lr - lb; }
    else if (c == 1) { u = lg - lr; v = lg - lb; }
    else             { u = lb - lr; v = lb - lg; }
    stage[w][0][l] = u * 50.f;     // u/sigma
    stage[w][1][l] = v * 50.f;
    stage[w][2][l] = iy;

    if (it + 1 < NIT) {  // prefetch next 64 pixels
      const int p = p0 + (it + 1) * 64 + l;
      pr = base[p]; pg = base[NPIX + p]; pb = base[2 * NPIX + p];
    }
    // wave-private LDS: in-order per wave; waitcnt orders write->read
    asm volatile("s_waitcnt lgkmcnt(0)" ::: "memory");

    // ---- two K-subtiles of 32 pixels each ----
#pragma unroll
    for (int s = 0; s < 2; ++s) {
      const int k0 = s * 32 + grp * 8;   // this lane's 8 pixels
      const f32x2* __restrict__ u2  = (const f32x2*)&stage[w][0][k0];
      const f32x2* __restrict__ v2  = (const f32x2*)&stage[w][1][k0];
      const f32x2* __restrict__ iy2 = (const f32x2*)&stage[w][2][k0];

      bf16x8 af[4];
#pragma unroll
      for (int ut = 0; ut < 4; ++ut) {
        const float dlt = d50_0 + (float)ut * dstep50;
        const f32x2 dlt2 = {dlt, dlt};
#pragma unroll
        for (int jp = 0; jp < 4; ++jp) {
          f32x2 x = u2[jp] - dlt2;
          f32x2 q = x * x + one2;                 // v_pk_fma candidates
          f32x2 rc = {__builtin_amdgcn_rcpf(q[0]), __builtin_amdgcn_rcpf(q[1])};
          f32x2 a2 = iy2[jp] * rc;
          af[ut][2 * jp]     = (__bf16)a2[0];
          af[ut][2 * jp + 1] = (__bf16)a2[1];
        }
      }

#pragma unroll
      for (int vt = 0; vt < 4; ++vt) {
        const float dlt = d50_0 + (float)vt * dstep50;
        const f32x2 dlt2 = {dlt, dlt};
        bf16x8 bf;
#pragma unroll
        for (int jp = 0; jp < 4; ++jp) {
          f32x2 x = v2[jp] - dlt2;
          f32x2 q = x * x + one2;
          bf[2 * jp]     = (__bf16)__builtin_amdgcn_rcpf(q[0]);
          bf[2 * jp + 1] = (__bf16)__builtin_amdgcn_rcpf(q[1]);
        }
#pragma unroll
        for (int ut = 0; ut < 4; ++ut)
          acc[ut * 4 + vt] =
              __builtin_amdgcn_mfma_f32_16x16x32_bf16(af[ut], bf, acc[ut * 4 + vt], 0, 0, 0);
      }
    }
  }

  // ---- vectorized tree reduction: (0+2),(1+3) -> (0+1) ----
  if (w >= 2) {
#pragma unroll
    for (int i = 0; i < 16; ++i) slab[w - 2][i][l] = acc[i];
  }
  __syncthreads();
  if (w < 2) {
#pragma unroll
    for (int i = 0; i < 16; ++i) acc[i] += slab[w][i][l];
  }
  __syncthreads();
  if (w == 1) {
#pragma unroll
    for (int i = 0; i < 16; ++i) slab[0][i][l] = acc[i];
  }
  __syncthreads();
  if (w == 0) {
    // store block partial in fragment layout: flat f32x4 index = i*64 + l
    f32x4* __restrict__ Pv = (f32x4*)(P + (size_t)blk * 4096);
#pragma unroll
    for (int i = 0; i < 16; ++i) Pv[i * 64 + l] = acc[i] + slab[0][i][l];
  }
}

// ---- stage 2: parallel partial reduction (elementwise; layout-agnostic) ----
// grid 384 x 256: thread e = (bc, si). Sums SEGB partials in-place into the
// segment-0 slice of P and atomically accumulates per-b norm.
template <int SEGB>
__global__ __launch_bounds__(256) void reduce_partials(float* __restrict__ P,
                                                       float* __restrict__ norms) {
  const int e  = blockIdx.x * 256 + threadIdx.x;   // 0..98303
  const int bc = e >> 12;
  const int si = e & 4095;
  float* __restrict__ p0 = P + (size_t)(bc * SEGB) * 4096 + si;
  float s = 0.f;
#pragma unroll
  for (int sg = 0; sg < SEGB; ++sg) s += p0[(size_t)sg * 4096];
  p0[0] = s;

  __shared__ float red[4];
  float ns = s;
#pragma unroll
  for (int off = 32; off > 0; off >>= 1) ns += __shfl_down(ns, off);
  if ((threadIdx.x & 63) == 0) red[threadIdx.x >> 6] = ns;
  __syncthreads();
  if (threadIdx.x == 0)
    atomicAdd(&norms[bc / 3], red[0] + red[1] + red[2] + red[3]);
}

// ---- stage 3: Hellinger loss + fused final (last block writes out) ----
template <int SEGB>
__global__ __launch_bounds__(256) void loss_final(const float* __restrict__ P,
                                                  const float* __restrict__ norms,
                                                  const float* __restrict__ th,
                                                  float* __restrict__ acc,
                                                  unsigned* __restrict__ counter,
                                                  float* __restrict__ out) {
  float s = 0.f;
  for (int idx = blockIdx.x * 256 + threadIdx.x; idx < 8 * 12288;
       idx += gridDim.x * 256) {
    const int b  = idx / 12288;
    const int r  = idx - b * 12288;
    const int c  = r >> 12;
    const int si = r & 4095;                 // fragment-permuted storage index
    // inverse permutation: si = ((i*64 + l)<<2)|rg  ->  (row,col)
    const int rg = si & 3;
    const int q  = si >> 2;
    const int l  = q & 63;
    const int i  = q >> 6;
    const int row = (i >> 2) * 16 + (l >> 4) * 4 + rg;
    const int col = (i & 3) * 16 + (l & 15);
    const float h = P[(size_t)((b * 3 + c) * SEGB) * 4096 + si] / (norms[b] + HEPS);
    const float d = sqrtf(th[c * 4096 + row * 64 + col]) - sqrtf(h);
    s += d * d;
  }
  __shared__ float red[4];
#pragma unroll
  for (int off = 32; off > 0; off >>= 1) s += __shfl_down(s, off);
  if ((threadIdx.x & 63) == 0) red[threadIdx.x >> 6] = s;
  __syncthreads();
  if (threadIdx.x == 0) {
    atomicAdd(acc, red[0] + red[1] + red[2] + red[3]);
    __threadfence();
    const unsigned old = atomicAdd(counter, 1u);
    if (old == (unsigned)(gridDim.x - 1)) {
      const float tot = atomicAdd(acc, 0.f);   // all adds visible
      out[0] = sqrtf(tot) * 0.08838834764831845f;   // (1/sqrt(2))/B, B=8
    }
  }
}

template <int SEGB>
static void run_path(const float* rgbd, const float* th, float* out,
                     void* d_ws, hipStream_t stream) {
  const size_t nP = (size_t)24 * SEGB * 4096;
  float*    P       = (float*)d_ws;
  float*    ctrl    = P + nP;                   // norms[8], acc, counter, pad
  float*    norms   = ctrl;
  float*    acc     = ctrl + 8;
  unsigned* counter = (unsigned*)(ctrl + 9);

  hist_mfma<SEGB><<<24 * SEGB, 256, 0, stream>>>(rgbd, P, ctrl);
  reduce_partials<SEGB><<<384, 256, 0, stream>>>(P, norms);
  loss_final<SEGB><<<96, 256, 0, stream>>>(P, norms, th, acc, counter, out);
}

extern "C" void kernel_launch(void* const* d_in, const int* in_sizes, int n_in,
                              void* d_out, int out_size, void* d_ws, size_t ws_size,
                              hipStream_t stream) {
  const float* rgbd = (const float*)d_in[0];   // [8,4,256,256]
  const float* th   = (const float*)d_in[1];   // [3,64,64]
  float* out = (float*)d_out;

  const size_t need64 = ((size_t)24 * 64 * 4096 + 64) * sizeof(float);  // 25.2 MB
  if (ws_size >= need64)
    run_path<64>(rgbd, th, out, d_ws, stream);
  else
    run_path<32>(rgbd, th, out, d_ws, stream);
}

// Round 8
// 113.833 us; speedup vs baseline: 1.1080x; 1.1080x over previous
//
#include <hip/hip_runtime.h>
#include <hip/hip_bf16.h>
#include <math.h>

#define NPIX 65536      // 256*256
#define SEGB 32         // segments per (b,c): 768 blocks = 3 blocks/CU (reg-capped fit)
#define HEPS (6.4f / 255.0f)

typedef __bf16 bf16x8 __attribute__((ext_vector_type(8)));
typedef float  f32x4  __attribute__((ext_vector_type(4)));

__device__ __forceinline__ float clamp01(float x) { return fminf(fmaxf(x, 0.f), 1.f); }

// grid: 24*SEGB blocks, 256 threads (4 waves). Round-5 measured-best geometry
// (43.9 us). This round: b128 stage reads, packed bf16 cvt, rolled NIT loop.
// Each wave: full 64x64 hist for its 512 pixels via 4x4 tiles of
// mfma_f32_16x16x32_bf16. Partial stored in FRAGMENT-PERMUTED layout.
// Block 0 zero-inits the 16-float control region (norms/acc/counter).
__global__ __launch_bounds__(256) void hist_mfma(const float* __restrict__ rgbd,
                                                 float* __restrict__ P,
                                                 float* __restrict__ ctrl) {
  const int blk = blockIdx.x;
  const int seg = blk & (SEGB - 1);
  const int bc  = blk / SEGB;     // 0..23
  const int b = bc / 3;
  const int c = bc - 3 * b;
  const int t = threadIdx.x;
  const int l = t & 63;
  const int w = t >> 6;           // wave 0..3

  if (blk == 0 && t < 16) ctrl[t] = 0.f;   // norms[8], acc, counter, pad

  __shared__ float stage[4][3][64];   // per-wave u50/v50/iy staging
  __shared__ f32x4 slab[2][16][64];   // reduction slabs (fragment layout)

  const float* __restrict__ base = rgbd + (size_t)b * (4 * NPIX);

  f32x4 acc[16];
#pragma unroll
  for (int i = 0; i < 16; ++i) acc[i] = (f32x4){0.f, 0.f, 0.f, 0.f};

  const int halfq = l & 15;   // output col within 16-tile
  const int grp   = l >> 4;   // k-group / output row group
  const float d50_0   = (-3.f + (float)halfq * (6.f / 63.f)) * 50.f;  // delta/sigma
  const float dstep50 = (16.f * 6.f / 63.f) * 50.f;

  const int p0 = seg * 2048 + w * 512;   // this wave's 512 pixels

  float pr = base[p0 + l];
  float pg = base[NPIX + p0 + l];
  float pb = base[2 * NPIX + p0 + l];

#pragma unroll 1
  for (int it = 0; it < 8; ++it) {
    // ---- per-pixel scalars ----
    float r  = clamp01(fmaf(pr, 0.5f, 0.5f));
    float g  = clamp01(fmaf(pg, 0.5f, 0.5f));
    float bl = clamp01(fmaf(pb, 0.5f, 0.5f));
    float iy = sqrtf(fmaf(r, r, fmaf(g, g, fmaf(bl, bl, HEPS))));
    float lr = __logf(r + HEPS);
    float lg = __logf(g + HEPS);
    float lb = __logf(bl + HEPS);
    float u, v;
    if (c == 0)      { u = lr - lg; v = lr - lb; }
    else if (c == 1) { u = lg - lr; v = lg - lb; }
    else             { u = lb - lr; v = lb - lg; }
    stage[w][0][l] = u * 50.f;     // u/sigma
    stage[w][1][l] = v * 50.f;
    stage[w][2][l] = iy;

    if (it + 1 < 8) {  // prefetch next 64 pixels
      const int p = p0 + (it + 1) * 64 + l;
      pr = base[p]; pg = base[NPIX + p]; pb = base[2 * NPIX + p];
    }
    // wave-private LDS: in-order per wave; waitcnt orders write->read
    asm volatile("s_waitcnt lgkmcnt(0)" ::: "memory");

    // ---- two K-subtiles of 32 pixels each ----
#pragma unroll
    for (int s = 0; s < 2; ++s) {
      const int k0 = s * 32 + grp * 8;   // this lane's 8 pixels (32B-aligned)
      // all stage reads for this subtile upfront: 6x ds_read_b128
      const f32x4 uA = *(const f32x4*)&stage[w][0][k0];
      const f32x4 uB = *(const f32x4*)&stage[w][0][k0 + 4];
      const f32x4 vA = *(const f32x4*)&stage[w][1][k0];
      const f32x4 vB = *(const f32x4*)&stage[w][1][k0 + 4];
      const f32x4 iA = *(const f32x4*)&stage[w][2][k0];
      const f32x4 iB = *(const f32x4*)&stage[w][2][k0 + 4];

      bf16x8 af[4];
#pragma unroll
      for (int ut = 0; ut < 4; ++ut) {
        const float dlt = d50_0 + (float)ut * dstep50;
#pragma unroll
        for (int jp = 0; jp < 4; ++jp) {
          const float u0 = (jp < 2 ? uA[2 * jp]     : uB[2 * jp - 4]) - dlt;
          const float u1 = (jp < 2 ? uA[2 * jp + 1] : uB[2 * jp - 3]) - dlt;
          const float i0 = (jp < 2 ? iA[2 * jp]     : iB[2 * jp - 4]);
          const float i1 = (jp < 2 ? iA[2 * jp + 1] : iB[2 * jp - 3]);
          const float a0 = i0 * __builtin_amdgcn_rcpf(fmaf(u0, u0, 1.f));
          const float a1 = i1 * __builtin_amdgcn_rcpf(fmaf(u1, u1, 1.f));
          ((__hip_bfloat162*)&af[ut])[jp] =
              __float22bfloat162_rn(make_float2(a0, a1));   // v_cvt_pk_bf16_f32
        }
      }

#pragma unroll
      for (int vt = 0; vt < 4; ++vt) {
        const float dlt = d50_0 + (float)vt * dstep50;
        bf16x8 bf;
#pragma unroll
        for (int jp = 0; jp < 4; ++jp) {
          const float v0 = (jp < 2 ? vA[2 * jp]     : vB[2 * jp - 4]) - dlt;
          const float v1 = (jp < 2 ? vA[2 * jp + 1] : vB[2 * jp - 3]) - dlt;
          const float k0f = __builtin_amdgcn_rcpf(fmaf(v0, v0, 1.f));
          const float k1f = __builtin_amdgcn_rcpf(fmaf(v1, v1, 1.f));
          ((__hip_bfloat162*)&bf)[jp] =
              __float22bfloat162_rn(make_float2(k0f, k1f));
        }
#pragma unroll
        for (int ut = 0; ut < 4; ++ut)
          acc[ut * 4 + vt] =
              __builtin_amdgcn_mfma_f32_16x16x32_bf16(af[ut], bf, acc[ut * 4 + vt], 0, 0, 0);
      }
    }
  }

  // ---- vectorized tree reduction: (0+2),(1+3) -> (0+1) ----
  if (w >= 2) {
#pragma unroll
    for (int i = 0; i < 16; ++i) slab[w - 2][i][l] = acc[i];
  }
  __syncthreads();
  if (w < 2) {
#pragma unroll
    for (int i = 0; i < 16; ++i) acc[i] += slab[w][i][l];
  }
  __syncthreads();
  if (w == 1) {
#pragma unroll
    for (int i = 0; i < 16; ++i) slab[0][i][l] = acc[i];
  }
  __syncthreads();
  if (w == 0) {
    // store block partial in fragment layout: flat f32x4 index = i*64 + l
    f32x4* __restrict__ Pv = (f32x4*)(P + (size_t)blk * 4096);
#pragma unroll
    for (int i = 0; i < 16; ++i) Pv[i * 64 + l] = acc[i] + slab[0][i][l];
  }
}

// ---- stage 2: parallel partial reduction (elementwise; layout-agnostic) ----
// grid 384 x 256: thread e = (bc, si). Sums SEGB partials in-place into the
// segment-0 slice of P and atomically accumulates per-b norm.
__global__ __launch_bounds__(256) void reduce_partials(float* __restrict__ P,
                                                       float* __restrict__ norms) {
  const int e  = blockIdx.x * 256 + threadIdx.x;   // 0..98303
  const int bc = e >> 12;
  const int si = e & 4095;
  float* __restrict__ p0 = P + (size_t)(bc * SEGB) * 4096 + si;
  float s = 0.f;
#pragma unroll
  for (int sg = 0; sg < SEGB; ++sg) s += p0[(size_t)sg * 4096];
  p0[0] = s;

  __shared__ float red[4];
  float ns = s;
#pragma unroll
  for (int off = 32; off > 0; off >>= 1) ns += __shfl_down(ns, off);
  if ((threadIdx.x & 63) == 0) red[threadIdx.x >> 6] = ns;
  __syncthreads();
  if (threadIdx.x == 0)
    atomicAdd(&norms[bc / 3], red[0] + red[1] + red[2] + red[3]);
}

// ---- stage 3: Hellinger loss + fused final (last block writes out) ----
__global__ __launch_bounds__(256) void loss_final(const float* __restrict__ P,
                                                  const float* __restrict__ norms,
                                                  const float* __restrict__ th,
                                                  float* __restrict__ acc,
                                                  unsigned* __restrict__ counter,
                                                  float* __restrict__ out) {
  float s = 0.f;
  for (int idx = blockIdx.x * 256 + threadIdx.x; idx < 8 * 12288;
       idx += gridDim.x * 256) {
    const int b  = idx / 12288;
    const int r  = idx - b * 12288;
    const int c  = r >> 12;
    const int si = r & 4095;                 // fragment-permuted storage index
    // inverse permutation: si = ((i*64 + l)<<2)|rg  ->  (row,col)
    const int rg = si & 3;
    const int q  = si >> 2;
    const int l  = q & 63;
    const int i  = q >> 6;
    const int row = (i >> 2) * 16 + (l >> 4) * 4 + rg;
    const int col = (i & 3) * 16 + (l & 15);
    const float h = P[(size_t)((b * 3 + c) * SEGB) * 4096 + si] / (norms[b] + HEPS);
    const float d = sqrtf(th[c * 4096 + row * 64 + col]) - sqrtf(h);
    s += d * d;
  }
  __shared__ float red[4];
#pragma unroll
  for (int off = 32; off > 0; off >>= 1) s += __shfl_down(s, off);
  if ((threadIdx.x & 63) == 0) red[threadIdx.x >> 6] = s;
  __syncthreads();
  if (threadIdx.x == 0) {
    atomicAdd(acc, red[0] + red[1] + red[2] + red[3]);
    __threadfence();
    const unsigned old = atomicAdd(counter, 1u);
    if (old == (unsigned)(gridDim.x - 1)) {
      const float tot = atomicAdd(acc, 0.f);   // all adds visible
      out[0] = sqrtf(tot) * 0.08838834764831845f;   // (1/sqrt(2))/B, B=8
    }
  }
}

extern "C" void kernel_launch(void* const* d_in, const int* in_sizes, int n_in,
                              void* d_out, int out_size, void* d_ws, size_t ws_size,
                              hipStream_t stream) {
  const float* rgbd = (const float*)d_in[0];   // [8,4,256,256]
  const float* th   = (const float*)d_in[1];   // [3,64,64]
  float* out = (float*)d_out;

  const size_t nP = (size_t)24 * SEGB * 4096;   // partial hists (12.6 MB)
  float*    P       = (float*)d_ws;
  float*    ctrl    = P + nP;                   // norms[8], acc, counter, pad
  float*    norms   = ctrl;
  float*    acc     = ctrl + 8;
  unsigned* counter = (unsigned*)(ctrl + 9);

  hist_mfma<<<24 * SEGB, 256, 0, stream>>>(rgbd, P, ctrl);
  reduce_partials<<<384, 256, 0, stream>>>(P, norms);
  loss_final<<<96, 256, 0, stream>>>(P, norms, th, acc, counter, out);
}